// Round 4
// baseline (135.820 us; speedup 1.0000x reference)
//
#include <hip/hip_runtime.h>
#include <hip/hip_bf16.h>

// Batched matmul: [24,1024,64] fp32 x [24,64,1024] fp32 -> [24,1024,1024] fp32.
// R4: ONE fused kernel. MFMA fragments built directly from fp32 global memory
// (A: k-contiguous dwordx4 pairs per lane; B: coalesced per-k scalar loads,
// 2 full 128-B lines per instr), fp32->bf16 RNE in-register. Epilogue does a
// per-wave 32x32 transpose through LDS so the 100 MB output is written with
// fully-coalesced non-temporal dwordx4 stores (8 full lines per instr).

#define NN 1024

typedef __attribute__((ext_vector_type(4))) float  float4v;
typedef __attribute__((ext_vector_type(8))) short  bf16x8;    // 8 bf16 = 4 VGPRs
typedef __attribute__((ext_vector_type(16))) float floatx16;  // 32x32 MFMA acc

// fp32 -> bf16 bits, round-to-nearest-even (inputs finite)
__device__ __forceinline__ short f2bs(float f) {
    union { float f; unsigned u; } in;
    in.f = f;
    unsigned u = in.u;
    return (short)((u + 0x7FFFu + ((u >> 16) & 1u)) >> 16);
}

// 32x32x16 bf16 fragment: lane = (idx&31) + ((k>>3)&1)*32, holds k = ks*16 + q*8 .. +7
// C/D layout (non-swapped): col = lane&31 -> n, row = (r&3) + 8*(r>>2) + 4*(lane>>5) -> m
__global__ __launch_bounds__(256) void bmm_fused(const float* __restrict__ A,
                                                 const float* __restrict__ B,
                                                 float* __restrict__ C) {
    __shared__ __align__(16) float tr[4][1024];  // per-wave 32x32 fp32 transpose buffer

    const int tid  = threadIdx.x;
    const int lane = tid & 63;
    const int w    = tid >> 6;
    const int bx = blockIdx.x;   // n-tile128 0..7
    const int by = blockIdx.y;   // m-tile128 0..7
    const int bh = blockIdx.z;   // 0..23
    const int wm = (w >> 1) * 2; // 32-tile base in m within 128-tile
    const int wn = (w & 1) * 2;
    const int lid = lane & 31;   // m (A) or n (B) within the 32-tile
    const int q   = lane >> 5;   // k-half selector

    const float* Abase = A + (size_t)bh * 65536;   // [1024][64] row-major
    const float* Bbase = B + (size_t)bh * 65536;   // [64][1024]

    floatx16 acc[2][2];
    #pragma unroll
    for (int mi = 0; mi < 2; ++mi)
        #pragma unroll
        for (int ni = 0; ni < 2; ++ni)
            #pragma unroll
            for (int r = 0; r < 16; ++r)
                acc[mi][ni][r] = 0.0f;

    const float* pa0 = Abase + (size_t)(by * 128 + (wm + 0) * 32 + lid) * 64 + q * 8;
    const float* pa1 = Abase + (size_t)(by * 128 + (wm + 1) * 32 + lid) * 64 + q * 8;
    const int n0 = bx * 128 + (wn + 0) * 32 + lid;
    const int n1 = bx * 128 + (wn + 1) * 32 + lid;

    #pragma unroll
    for (int ks = 0; ks < 4; ++ks) {
        // A fragments: 32 B contiguous per lane (two aligned float4)
        float4v a0lo = *(const float4v*)(pa0 + ks * 16);
        float4v a0hi = *(const float4v*)(pa0 + ks * 16 + 4);
        float4v a1lo = *(const float4v*)(pa1 + ks * 16);
        float4v a1hi = *(const float4v*)(pa1 + ks * 16 + 4);
        // B fragments: 8 per-k coalesced scalar loads (lanes cover 2 full lines)
        const float* pb0 = Bbase + (size_t)(ks * 16 + q * 8) * NN + n0;
        const float* pb1 = Bbase + (size_t)(ks * 16 + q * 8) * NN + n1;

        bf16x8 a0, a1, b0, b1;
        a0[0]=f2bs(a0lo.x); a0[1]=f2bs(a0lo.y); a0[2]=f2bs(a0lo.z); a0[3]=f2bs(a0lo.w);
        a0[4]=f2bs(a0hi.x); a0[5]=f2bs(a0hi.y); a0[6]=f2bs(a0hi.z); a0[7]=f2bs(a0hi.w);
        a1[0]=f2bs(a1lo.x); a1[1]=f2bs(a1lo.y); a1[2]=f2bs(a1lo.z); a1[3]=f2bs(a1lo.w);
        a1[4]=f2bs(a1hi.x); a1[5]=f2bs(a1hi.y); a1[6]=f2bs(a1hi.z); a1[7]=f2bs(a1hi.w);
        #pragma unroll
        for (int j = 0; j < 8; ++j) b0[j] = f2bs(pb0[(size_t)j * NN]);
        #pragma unroll
        for (int j = 0; j < 8; ++j) b1[j] = f2bs(pb1[(size_t)j * NN]);

        acc[0][0] = __builtin_amdgcn_mfma_f32_32x32x16_bf16(a0, b0, acc[0][0], 0, 0, 0);
        acc[0][1] = __builtin_amdgcn_mfma_f32_32x32x16_bf16(a0, b1, acc[0][1], 0, 0, 0);
        acc[1][0] = __builtin_amdgcn_mfma_f32_32x32x16_bf16(a1, b0, acc[1][0], 0, 0, 0);
        acc[1][1] = __builtin_amdgcn_mfma_f32_32x32x16_bf16(a1, b1, acc[1][1], 0, 0, 0);
    }

    // ---- epilogue: per-wave 32x32 transpose via LDS, then nt dwordx4 stores ----
    const int rbase = q * 4;
    #pragma unroll
    for (int mi = 0; mi < 2; ++mi) {
        #pragma unroll
        for (int ni = 0; ni < 2; ++ni) {
            __syncthreads();  // WAR: previous tile's reads done before overwrite
            #pragma unroll
            for (int r = 0; r < 16; ++r) {
                int row = rbase + (r & 3) + (r >> 2) * 8;   // m within tile
                tr[w][row * 32 + lid] = acc[mi][ni][r];     // bank=lid, 2-way (free)
            }
            __syncthreads();  // RAW: cross-lane reads see all writes
            float* Ct = C + ((size_t)bh << 20)
                          + (size_t)(by * 128 + (wm + mi) * 32) * NN
                          + bx * 128 + (wn + ni) * 32;
            #pragma unroll
            for (int g = 0; g < 4; ++g) {
                float4v v = *(const float4v*)&tr[w][g * 256 + lane * 4];  // ds_read_b128
                int row = g * 8 + (lane >> 3);
                __builtin_nontemporal_store(
                    v, (float4v*)(Ct + (size_t)row * NN + (lane & 7) * 4));
            }
        }
    }
}

extern "C" void kernel_launch(void* const* d_in, const int* in_sizes, int n_in,
                              void* d_out, int out_size, void* d_ws, size_t ws_size,
                              hipStream_t stream) {
    const float* x1 = (const float*)d_in[0];   // [2,12,1024,64]
    const float* x2 = (const float*)d_in[1];   // [2,12,64,1024]
    float* out = (float*)d_out;                // [2,12,1024,1024] fp32
    (void)d_ws; (void)ws_size; (void)in_sizes; (void)n_in; (void)out_size;

    hipLaunchKernelGGL(bmm_fused, dim3(8, 8, 24), dim3(256), 0, stream, x1, x2, out);
}

// Round 6
// 122.022 us; speedup vs baseline: 1.1131x; 1.1131x over previous
//
#include <hip/hip_runtime.h>
#include <hip/hip_bf16.h>

// Batched matmul: [24,1024,64] fp32 x [24,64,1024] fp32 -> [24,1024,1024] fp32.
// R6 = R3 structure (best: 123.3us) with a higher-parallelism reformat:
//   - reformat: 1536 blocks x 1 task (6 blocks/CU to hide ~900cyc cold-HBM
//     latency; was 384 x 4), nontemporal input loads (read-once, don't
//     allocate L2 -> keep the 6.3MB ws fragments hot instead).
//   - GEMM: byte-identical to R3. LDS-free, barrier-free; fragment loads are
//     fully-coalesced dwordx4; non-swapped MFMA so each nt scalar store instr
//     covers 2 full 128-B lines of the 100MB output stream.

#define NN 1024

typedef __attribute__((ext_vector_type(4))) float  float4v;
typedef __attribute__((ext_vector_type(8))) short  bf16x8;    // 8 bf16 = 16 B
typedef __attribute__((ext_vector_type(16))) float floatx16;  // 32x32 MFMA acc

// fp32 -> bf16 bits, round-to-nearest-even (inputs finite)
__device__ __forceinline__ short f2bs(float f) {
    union { float f; unsigned u; } in;
    in.f = f;
    unsigned u = in.u;
    return (short)((u + 0x7FFFu + ((u >> 16) & 1u)) >> 16);
}

// Fragment layout (32x32x16 bf16; verified end-to-end R1-R3):
//   element (idx, k): tile = idx>>5, ks = k>>4, q = (k>>3)&1, j = k&7
//   lane = (idx&31) + q*32, short addr = ((bh*32+tile)*4 + ks)*512 + lane*8 + j
// A indexed by m over [m][k] row-major; B indexed by n over [k][n].

// Reformat: blocks 0..767 handle A (one task/thread), 768..1535 handle B.
__global__ __launch_bounds__(256) void reformat_AB(const float* __restrict__ A,
                                                   const float* __restrict__ B,
                                                   short* __restrict__ Aw,
                                                   short* __restrict__ Bw) {
    const int bid = blockIdx.x;
    if (bid < 768) {
        int task = bid * 256 + threadIdx.x;      // 0..196607  [bh][m][kg]
        int bh   = task >> 13;
        int rem  = task & 8191;
        int m    = rem >> 3;
        int kg   = rem & 7;
        const float4v* p = (const float4v*)(A + (size_t)task * 8);
        float4v v0 = __builtin_nontemporal_load(p);
        float4v v1 = __builtin_nontemporal_load(p + 1);
        int ks = kg >> 1, q = kg & 1;
        int mt = m >> 5;
        int lane = (m & 31) + (q << 5);
        size_t dst = ((size_t)((bh * 32 + mt) * 4 + ks)) * 512 + (size_t)lane * 8;
        bf16x8 o;
        o[0] = f2bs(v0.x); o[1] = f2bs(v0.y); o[2] = f2bs(v0.z); o[3] = f2bs(v0.w);
        o[4] = f2bs(v1.x); o[5] = f2bs(v1.y); o[6] = f2bs(v1.z); o[7] = f2bs(v1.w);
        *(bf16x8*)(Aw + dst) = o;
    } else {
        int task = (bid - 768) * 256 + threadIdx.x;  // 0..196607  [kg][bh][n]
        int kg   = task / 24576;                 // 0..7
        int rem  = task - kg * 24576;
        int bh   = rem >> 10;
        int n    = rem & 1023;
        const float* p = B + (size_t)bh * 65536 + (size_t)kg * 8192 + n;
        float v0 = __builtin_nontemporal_load(p + 0 * 1024);
        float v1 = __builtin_nontemporal_load(p + 1 * 1024);
        float v2 = __builtin_nontemporal_load(p + 2 * 1024);
        float v3 = __builtin_nontemporal_load(p + 3 * 1024);
        float v4 = __builtin_nontemporal_load(p + 4 * 1024);
        float v5 = __builtin_nontemporal_load(p + 5 * 1024);
        float v6 = __builtin_nontemporal_load(p + 6 * 1024);
        float v7 = __builtin_nontemporal_load(p + 7 * 1024);
        int ks = kg >> 1, q = kg & 1;
        int nt = n >> 5;
        int lane = (n & 31) + (q << 5);
        size_t dst = ((size_t)((bh * 32 + nt) * 4 + ks)) * 512 + (size_t)lane * 8;
        bf16x8 o;
        o[0] = f2bs(v0); o[1] = f2bs(v1); o[2] = f2bs(v2); o[3] = f2bs(v3);
        o[4] = f2bs(v4); o[5] = f2bs(v5); o[6] = f2bs(v6); o[7] = f2bs(v7);
        *(bf16x8*)(Bw + dst) = o;
    }
}

// GEMM: no LDS, no syncthreads. Each wave: 64x64 output (2x2 of 32x32).
// Non-swapped mfma(a,b,acc): col = lane&31 -> n (contiguous across lanes),
// row = (r&3)+8*(r>>2)+4*(lane>>5) -> m. Each scalar store instr covers
// exactly 2 full 128-B lines. Non-temporal stores (pure 100MB stream).
__global__ __launch_bounds__(256) void bmm_frag(const short* __restrict__ Aw,
                                                const short* __restrict__ Bw,
                                                float* __restrict__ C) {
    const int tid  = threadIdx.x;
    const int lane = tid & 63;
    const int w    = tid >> 6;
    const int bx = blockIdx.x;   // n-tile128 0..7
    const int by = blockIdx.y;   // m-tile128 0..7
    const int bh = blockIdx.z;   // 0..23
    const int wm = (w >> 1) * 2; // 32-tile base in m within the 128 tile
    const int wn = (w & 1) * 2;

    const short* Ab = Aw + ((size_t)((bh * 32 + by * 4 + wm) * 4)) * 512 + (size_t)lane * 8;
    const short* Bb = Bw + ((size_t)((bh * 32 + bx * 4 + wn) * 4)) * 512 + (size_t)lane * 8;
    // next 32-tile: +2048 shorts; next ks: +512 shorts

    floatx16 acc[2][2];
    #pragma unroll
    for (int mi = 0; mi < 2; ++mi)
        #pragma unroll
        for (int ni = 0; ni < 2; ++ni)
            #pragma unroll
            for (int r = 0; r < 16; ++r)
                acc[mi][ni][r] = 0.0f;

    #pragma unroll
    for (int ks = 0; ks < 4; ++ks) {
        bf16x8 a0 = *(const bf16x8*)(Ab + ks * 512);
        bf16x8 a1 = *(const bf16x8*)(Ab + 2048 + ks * 512);
        bf16x8 b0 = *(const bf16x8*)(Bb + ks * 512);
        bf16x8 b1 = *(const bf16x8*)(Bb + 2048 + ks * 512);
        acc[0][0] = __builtin_amdgcn_mfma_f32_32x32x16_bf16(a0, b0, acc[0][0], 0, 0, 0);
        acc[0][1] = __builtin_amdgcn_mfma_f32_32x32x16_bf16(a0, b1, acc[0][1], 0, 0, 0);
        acc[1][0] = __builtin_amdgcn_mfma_f32_32x32x16_bf16(a1, b0, acc[1][0], 0, 0, 0);
        acc[1][1] = __builtin_amdgcn_mfma_f32_32x32x16_bf16(a1, b1, acc[1][1], 0, 0, 0);
    }

    const int nc    = lane & 31;        // n within 32-tile (contiguous across lanes)
    const int rbase = (lane >> 5) * 4;  // m sub-base
    float* Cb = C + ((size_t)bh << 20)
                  + (size_t)(by * 128 + wm * 32) * NN
                  + bx * 128 + wn * 32 + nc;

    #pragma unroll
    for (int mi = 0; mi < 2; ++mi) {
        #pragma unroll
        for (int ni = 0; ni < 2; ++ni) {
            float* Ct = Cb + (size_t)(mi * 32) * NN + ni * 32;
            #pragma unroll
            for (int r = 0; r < 16; ++r) {
                int row = rbase + (r & 3) + ((r >> 2) * 8);
                __builtin_nontemporal_store(acc[mi][ni][r], Ct + (size_t)row * NN);
            }
        }
    }
}

extern "C" void kernel_launch(void* const* d_in, const int* in_sizes, int n_in,
                              void* d_out, int out_size, void* d_ws, size_t ws_size,
                              hipStream_t stream) {
    const float* x1 = (const float*)d_in[0];   // [2,12,1024,64]
    const float* x2 = (const float*)d_in[1];   // [2,12,64,1024]
    float* out = (float*)d_out;                // [2,12,1024,1024] fp32

    short* Aw = (short*)d_ws;                  // 1,572,864 bf16 = 3.1 MB
    short* Bw = Aw + 1572864;                  // 3.1 MB

    hipLaunchKernelGGL(reformat_AB, dim3(1536), dim3(256), 0, stream, x1, x2, Aw, Bw);
    hipLaunchKernelGGL(bmm_frag, dim3(8, 8, 24), dim3(256), 0, stream, Aw, Bw, out);
}